// Round 1
// baseline (2577.613 us; speedup 1.0000x reference)
//
#include <hip/hip_runtime.h>

// Performer attention (HyperGTConv): N=50000 nodes, C=256, H=8 heads, D=M=64.
// fp32 end-to-end (no fp32 MFMA on CDNA4 -> VALU). Three kernels:
//  1) kv_partial: per (slice, head) block accumulates partial KV[m,d], sum(Kp)
//  2) reduce_kernel: deterministic reduction of partials
//  3) out_kernel: Q -> Qp -> Z -> out, per 64-node chunk

#define NN      50000
#define C_IN    256
#define HH      8
#define DD      64
#define HDIM    512
#define MM      64
#define EPSF    1e-6f
// ratio * data_normalizer = (1/sqrt(64)) * 64^{-1/4}
#define SCALE   0.044194173824159224f
#define NCHUNK  782      // ceil(50000/64)
#define NBLK1   64       // partial slices per head

__global__ __launch_bounds__(256)
void kv_partial_kernel(const float* __restrict__ x,
                       const float* __restrict__ Wk, const float* __restrict__ bk,
                       const float* __restrict__ Wv, const float* __restrict__ bv,
                       const float* __restrict__ proj,
                       float* __restrict__ pKV, float* __restrict__ pSum)
{
    __shared__ __align__(16) float xs[64 * C_IN];   // 64 KB
    __shared__ __align__(16) float ks[64 * 64];
    __shared__ __align__(16) float vs[64 * 64];
    __shared__ __align__(16) float kp[64 * 64];
    __shared__ __align__(16) float pt[64 * 64];     // proj transposed: pt[d][m]

    const int t    = threadIdx.x;
    const int lane = t & 63;
    const int g    = t >> 6;          // 0..3
    const int h    = blockIdx.y;
    const int bx   = blockIdx.x;

    // stage proj^T once
    for (int idx = t; idx < 64 * 64; idx += 256) {
        const int m = idx >> 6, d = idx & 63;
        pt[d * 64 + m] = proj[idx];
    }

    const int   col = h * 64 + lane;
    const float bkc = bk[col];
    const float bvc = bv[col];

    float accKV[16];
#pragma unroll
    for (int i = 0; i < 16; ++i) accKV[i] = 0.f;
    float accSum = 0.f;

    for (int chunk = bx; chunk < NCHUNK; chunk += NBLK1) {
        const int n0 = chunk * 64;
        __syncthreads();   // protect LDS from previous iteration's readers
        for (int idx = t; idx < 64 * C_IN; idx += 256) {
            const int r = idx >> 8;
            const int n = n0 + r;
            xs[idx] = (n < NN) ? x[(size_t)n * C_IN + (idx & 255)] : 0.f;
        }
        __syncthreads();

        // K,V GEMM: thread owns rows r = g + 4*i, column `col`
        float accK[16], accV[16];
#pragma unroll
        for (int i = 0; i < 16; ++i) { accK[i] = bkc; accV[i] = bvc; }
        for (int c = 0; c < C_IN; c += 4) {
            const float wk0 = Wk[(c + 0) * HDIM + col];
            const float wk1 = Wk[(c + 1) * HDIM + col];
            const float wk2 = Wk[(c + 2) * HDIM + col];
            const float wk3 = Wk[(c + 3) * HDIM + col];
            const float wv0 = Wv[(c + 0) * HDIM + col];
            const float wv1 = Wv[(c + 1) * HDIM + col];
            const float wv2 = Wv[(c + 2) * HDIM + col];
            const float wv3 = Wv[(c + 3) * HDIM + col];
#pragma unroll
            for (int i = 0; i < 16; ++i) {
                const float4 xv = *reinterpret_cast<const float4*>(&xs[(g + 4 * i) * C_IN + c]);
                accK[i] = fmaf(xv.x, wk0, fmaf(xv.y, wk1, fmaf(xv.z, wk2, fmaf(xv.w, wk3, accK[i]))));
                accV[i] = fmaf(xv.x, wv0, fmaf(xv.y, wv1, fmaf(xv.z, wv2, fmaf(xv.w, wv3, accV[i]))));
            }
        }
#pragma unroll
        for (int i = 0; i < 16; ++i) {
            ks[(g + 4 * i) * 64 + lane] = accK[i];
            vs[(g + 4 * i) * 64 + lane] = accV[i];
        }
        __syncthreads();

        // Kp = exp(SCALE * K . proj[m]) + eps (feature lane = m)
        {
            float acc[16];
#pragma unroll
            for (int i = 0; i < 16; ++i) acc[i] = 0.f;
            for (int d = 0; d < 64; d += 4) {
                const float p0 = pt[(d + 0) * 64 + lane];
                const float p1 = pt[(d + 1) * 64 + lane];
                const float p2 = pt[(d + 2) * 64 + lane];
                const float p3 = pt[(d + 3) * 64 + lane];
#pragma unroll
                for (int i = 0; i < 16; ++i) {
                    const float4 kv = *reinterpret_cast<const float4*>(&ks[(g + 4 * i) * 64 + d]);
                    acc[i] = fmaf(kv.x, p0, fmaf(kv.y, p1, fmaf(kv.z, p2, fmaf(kv.w, p3, acc[i]))));
                }
            }
#pragma unroll
            for (int i = 0; i < 16; ++i) {
                const int r = g + 4 * i;
                float v = __expf(SCALE * acc[i]) + EPSF;
                if (n0 + r >= NN) v = 0.f;   // invalid rows contribute nothing
                kp[r * 64 + lane] = v;
            }
        }
        __syncthreads();

        // KV[m][d] += Kp[r][m] * V[r][d]; thread owns m = g*16+i, d = lane
        for (int r = 0; r < 64; ++r) {
            const float vv = vs[r * 64 + lane];
            const float4 k0 = *reinterpret_cast<const float4*>(&kp[r * 64 + g * 16 + 0]);
            const float4 k1 = *reinterpret_cast<const float4*>(&kp[r * 64 + g * 16 + 4]);
            const float4 k2 = *reinterpret_cast<const float4*>(&kp[r * 64 + g * 16 + 8]);
            const float4 k3 = *reinterpret_cast<const float4*>(&kp[r * 64 + g * 16 + 12]);
            const float pk[16] = { k0.x, k0.y, k0.z, k0.w, k1.x, k1.y, k1.z, k1.w,
                                   k2.x, k2.y, k2.z, k2.w, k3.x, k3.y, k3.z, k3.w };
#pragma unroll
            for (int i = 0; i < 16; ++i) accKV[i] = fmaf(pk[i], vv, accKV[i]);
        }
        // Kp column sums (wave 0 only; m = lane)
        if (g == 0) {
            for (int r = 0; r < 64; ++r) accSum += kp[r * 64 + lane];
        }
    }

    // write this block's partial (deterministic layout [h][bx][m*64+d])
    float* dst = pKV + ((size_t)h * NBLK1 + bx) * 4096;
#pragma unroll
    for (int i = 0; i < 16; ++i) dst[(g * 16 + i) * 64 + lane] = accKV[i];
    if (g == 0) pSum[((size_t)h * NBLK1 + bx) * 64 + lane] = accSum;
}

__global__ void reduce_kernel(const float* __restrict__ pKV, const float* __restrict__ pSum,
                              float* __restrict__ KV, float* __restrict__ Ksum)
{
    const int idx = blockIdx.x * 256 + threadIdx.x;
    if (idx < HH * 4096) {
        const int h  = idx >> 12;
        const int md = idx & 4095;
        float s = 0.f;
        for (int b = 0; b < NBLK1; ++b) s += pKV[((size_t)h * NBLK1 + b) * 4096 + md];
        KV[idx] = s;
    } else {
        const int j = idx - HH * 4096;
        if (j < HH * 64) {
            const int h = j >> 6, m = j & 63;
            float s = 0.f;
            for (int b = 0; b < NBLK1; ++b) s += pSum[((size_t)h * NBLK1 + b) * 64 + m];
            Ksum[j] = s;
        }
    }
}

__global__ __launch_bounds__(256)
void out_kernel(const float* __restrict__ x,
                const float* __restrict__ Wq, const float* __restrict__ bq,
                const float* __restrict__ proj,
                const float* __restrict__ KV, const float* __restrict__ Ksum,
                const float* __restrict__ Wo, const float* __restrict__ bo,
                float* __restrict__ out)
{
    __shared__ __align__(16) float xs[64 * C_IN];   // 64 KB
    __shared__ __align__(16) float pt[64 * 64];
    __shared__ __align__(16) float qs[64 * 64];     // Q, later reused for Z
    __shared__ __align__(16) float qp[64 * 64];
    __shared__ __align__(16) float kvs[64 * 64];
    __shared__ float ksh[64];

    const int t    = threadIdx.x;
    const int lane = t & 63;
    const int g    = t >> 6;
    const int n0   = blockIdx.x * 64;

    for (int idx = t; idx < 64 * 64; idx += 256) {
        const int m = idx >> 6, d = idx & 63;
        pt[d * 64 + m] = proj[idx];
    }
    for (int idx = t; idx < 64 * C_IN; idx += 256) {
        const int r = idx >> 8;
        const int n = n0 + r;
        xs[idx] = (n < NN) ? x[(size_t)n * C_IN + (idx & 255)] : 0.f;
    }

    float accO[16];
    const float boc = bo[lane];
#pragma unroll
    for (int i = 0; i < 16; ++i) accO[i] = boc;

    __syncthreads();

    for (int h = 0; h < HH; ++h) {
        // Q GEMM into registers
        const int   col = h * 64 + lane;
        const float bqc = bq[col];
        float accQ[16];
#pragma unroll
        for (int i = 0; i < 16; ++i) accQ[i] = bqc;
        for (int c = 0; c < C_IN; c += 4) {
            const float w0 = Wq[(c + 0) * HDIM + col];
            const float w1 = Wq[(c + 1) * HDIM + col];
            const float w2 = Wq[(c + 2) * HDIM + col];
            const float w3 = Wq[(c + 3) * HDIM + col];
#pragma unroll
            for (int i = 0; i < 16; ++i) {
                const float4 xv = *reinterpret_cast<const float4*>(&xs[(g + 4 * i) * C_IN + c]);
                accQ[i] = fmaf(xv.x, w0, fmaf(xv.y, w1, fmaf(xv.z, w2, fmaf(xv.w, w3, accQ[i]))));
            }
        }
        // stage this head's KV and Ksum
        for (int idx = t; idx < 4096; idx += 256) kvs[idx] = KV[h * 4096 + idx];
        if (t < 64) ksh[t] = Ksum[h * 64 + t];
        __syncthreads();                    // B1: prev-iter qs readers done; kvs visible
#pragma unroll
        for (int i = 0; i < 16; ++i) qs[(g + 4 * i) * 64 + lane] = accQ[i];
        __syncthreads();                    // B2

        // Qp = exp(SCALE * Q . proj[m]) + eps
        float accP[16];
#pragma unroll
        for (int i = 0; i < 16; ++i) accP[i] = 0.f;
        for (int d = 0; d < 64; d += 4) {
            const float p0 = pt[(d + 0) * 64 + lane];
            const float p1 = pt[(d + 1) * 64 + lane];
            const float p2 = pt[(d + 2) * 64 + lane];
            const float p3 = pt[(d + 3) * 64 + lane];
#pragma unroll
            for (int i = 0; i < 16; ++i) {
                const float4 qv = *reinterpret_cast<const float4*>(&qs[(g + 4 * i) * 64 + d]);
                accP[i] = fmaf(qv.x, p0, fmaf(qv.y, p1, fmaf(qv.z, p2, fmaf(qv.w, p3, accP[i]))));
            }
        }
#pragma unroll
        for (int i = 0; i < 16; ++i)
            qp[(g + 4 * i) * 64 + lane] = __expf(SCALE * accP[i]) + EPSF;
        __syncthreads();                    // B3

        // Z = (Qp @ KV) / (Qp . Ksum + eps)
        float num[16], den[16];
#pragma unroll
        for (int i = 0; i < 16; ++i) { num[i] = 0.f; den[i] = 0.f; }
        for (int m = 0; m < 64; m += 4) {
            const float kv0 = kvs[(m + 0) * 64 + lane];
            const float kv1 = kvs[(m + 1) * 64 + lane];
            const float kv2 = kvs[(m + 2) * 64 + lane];
            const float kv3 = kvs[(m + 3) * 64 + lane];
            const float s0 = ksh[m + 0], s1 = ksh[m + 1], s2 = ksh[m + 2], s3 = ksh[m + 3];
#pragma unroll
            for (int i = 0; i < 16; ++i) {
                const float4 q4 = *reinterpret_cast<const float4*>(&qp[(g + 4 * i) * 64 + m]);
                num[i] = fmaf(q4.x, kv0, fmaf(q4.y, kv1, fmaf(q4.z, kv2, fmaf(q4.w, kv3, num[i]))));
                den[i] = fmaf(q4.x, s0, fmaf(q4.y, s1, fmaf(q4.z, s2, fmaf(q4.w, s3, den[i]))));
            }
        }
        __syncthreads();                    // B4
#pragma unroll
        for (int i = 0; i < 16; ++i)
            qs[(g + 4 * i) * 64 + lane] = num[i] / (den[i] + EPSF);
        __syncthreads();                    // B5

        // out += Z_h @ Wo[h*64 : h*64+64, :]   (thread column j = lane)
        for (int d = 0; d < 64; d += 4) {
            const float w0 = Wo[(h * 64 + d + 0) * DD + lane];
            const float w1 = Wo[(h * 64 + d + 1) * DD + lane];
            const float w2 = Wo[(h * 64 + d + 2) * DD + lane];
            const float w3 = Wo[(h * 64 + d + 3) * DD + lane];
#pragma unroll
            for (int i = 0; i < 16; ++i) {
                const float4 zv = *reinterpret_cast<const float4*>(&qs[(g + 4 * i) * 64 + d]);
                accO[i] = fmaf(zv.x, w0, fmaf(zv.y, w1, fmaf(zv.z, w2, fmaf(zv.w, w3, accO[i]))));
            }
        }
        // next h's B1 protects qs/kvs reuse
    }

#pragma unroll
    for (int i = 0; i < 16; ++i) {
        const int n = n0 + g + 4 * i;
        if (n < NN) out[(size_t)n * DD + lane] = accO[i];
    }
}

extern "C" void kernel_launch(void* const* d_in, const int* in_sizes, int n_in,
                              void* d_out, int out_size, void* d_ws, size_t ws_size,
                              hipStream_t stream) {
    const float* x    = (const float*)d_in[0];
    const float* Wq   = (const float*)d_in[1];
    const float* bq   = (const float*)d_in[2];
    const float* Wk   = (const float*)d_in[3];
    const float* bk   = (const float*)d_in[4];
    const float* Wv   = (const float*)d_in[5];
    const float* bv   = (const float*)d_in[6];
    const float* Wo   = (const float*)d_in[7];
    const float* bo   = (const float*)d_in[8];
    const float* proj = (const float*)d_in[9];
    float* out = (float*)d_out;

    // workspace layout (floats): pKV [8][64][4096], pSum [8][64][64], KV [8][4096], Ksum [8][64]
    float* ws   = (float*)d_ws;
    float* pKV  = ws;
    float* pSum = pKV  + (size_t)HH * NBLK1 * 4096;   // +2,097,152
    float* KV   = pSum + (size_t)HH * NBLK1 * 64;     // +32,768
    float* Ksum = KV   + (size_t)HH * 4096;           // +32,768   (total ~8.7 MB)

    kv_partial_kernel<<<dim3(NBLK1, HH), 256, 0, stream>>>(x, Wk, bk, Wv, bv, proj, pKV, pSum);
    reduce_kernel<<<dim3(130), 256, 0, stream>>>(pKV, pSum, KV, Ksum);
    out_kernel<<<dim3(NCHUNK), 256, 0, stream>>>(x, Wq, bq, proj, KV, Ksum, Wo, bo, out);
}

// Round 2
// 1288.043 us; speedup vs baseline: 2.0012x; 2.0012x over previous
//
#include <hip/hip_runtime.h>

// Performer attention (HyperGTConv): N=50000, C=256, H=8 heads, D=M=64, fp32.
// Round 2: occupancy fix. 32-row chunks -> LDS 72-74 KB -> 2 blocks/CU (8 waves/CU
// vs 4 before). float4 staging, dual-head Q-GEMM, distributed Kp column sums.

#define NN      50000
#define C_IN    256
#define HH      8
#define DD      64
#define HDIM    512
#define EPSF    1e-6f
// ratio * data_normalizer = (1/sqrt(64)) * 64^{-1/4}
#define SCALE   0.044194173824159224f

#define CH      32        // rows per chunk
#define NCHUNK  1563      // ceil(50000/32)
#define NSLICE  64        // kv partial slices per head (64*8 = 512 blocks = 2/CU exactly)

__global__ __launch_bounds__(256)
void kv_partial_kernel(const float* __restrict__ x,
                       const float* __restrict__ Wk, const float* __restrict__ bk,
                       const float* __restrict__ Wv, const float* __restrict__ bv,
                       const float* __restrict__ proj,
                       float* __restrict__ pKV, float* __restrict__ pSum)
{
    __shared__ __align__(16) float xs[CH * C_IN];   // 32 KB
    __shared__ __align__(16) float ks[CH * 64];     // 8 KB
    __shared__ __align__(16) float vs[CH * 64];     // 8 KB
    __shared__ __align__(16) float kp[CH * 64];     // 8 KB
    __shared__ __align__(16) float pt[64 * 64];     // 16 KB  -> 72 KB total, 2 blocks/CU

    const int t    = threadIdx.x;
    const int lane = t & 63;
    const int g    = t >> 6;          // 0..3
    const int h    = blockIdx.y;
    const int bx   = blockIdx.x;

    // stage proj^T once: pt[d][m] = proj[m][d]
    for (int idx = t; idx < 64 * 64; idx += 256)
        pt[(idx & 63) * 64 + (idx >> 6)] = proj[idx];

    const int   col = h * 64 + lane;
    const float bkc = bk[col];
    const float bvc = bv[col];

    float accKV[16];
#pragma unroll
    for (int i = 0; i < 16; ++i) accKV[i] = 0.f;
    float accSum = 0.f;

    for (int chunk = bx; chunk < NCHUNK; chunk += NSLICE) {
        const int n0 = chunk * CH;
        __syncthreads();   // protect xs/ks/vs/kp from previous iteration's readers
        // stage x chunk, float4-vectorized (CH*C_IN/4 = 2048 float4)
        for (int i4 = t; i4 < CH * 64; i4 += 256) {
            const int r = i4 >> 6;            // 64 float4 per row
            const int n = n0 + r;
            float4 v = make_float4(0.f, 0.f, 0.f, 0.f);
            if (n < NN) v = reinterpret_cast<const float4*>(x)[(size_t)n * 64 + (i4 & 63)];
            reinterpret_cast<float4*>(xs)[i4] = v;
        }
        __syncthreads();

        // K,V GEMM: thread owns rows r = g + 4*i (i<8), column `col`
        float accK[8], accV[8];
#pragma unroll
        for (int i = 0; i < 8; ++i) { accK[i] = bkc; accV[i] = bvc; }
        for (int c = 0; c < C_IN; c += 4) {
            const float wk0 = Wk[(c + 0) * HDIM + col];
            const float wk1 = Wk[(c + 1) * HDIM + col];
            const float wk2 = Wk[(c + 2) * HDIM + col];
            const float wk3 = Wk[(c + 3) * HDIM + col];
            const float wv0 = Wv[(c + 0) * HDIM + col];
            const float wv1 = Wv[(c + 1) * HDIM + col];
            const float wv2 = Wv[(c + 2) * HDIM + col];
            const float wv3 = Wv[(c + 3) * HDIM + col];
#pragma unroll
            for (int i = 0; i < 8; ++i) {
                const float4 xv = *reinterpret_cast<const float4*>(&xs[(g + 4 * i) * C_IN + c]);
                accK[i] = fmaf(xv.x, wk0, fmaf(xv.y, wk1, fmaf(xv.z, wk2, fmaf(xv.w, wk3, accK[i]))));
                accV[i] = fmaf(xv.x, wv0, fmaf(xv.y, wv1, fmaf(xv.z, wv2, fmaf(xv.w, wv3, accV[i]))));
            }
        }
#pragma unroll
        for (int i = 0; i < 8; ++i) {
            ks[(g + 4 * i) * 64 + lane] = accK[i];
            vs[(g + 4 * i) * 64 + lane] = accV[i];
        }
        __syncthreads();

        // Kp = exp(SCALE * K . proj[m]) + eps   (thread: rows r, feature m = lane)
        {
            float acc[8];
#pragma unroll
            for (int i = 0; i < 8; ++i) acc[i] = 0.f;
            for (int d = 0; d < 64; d += 4) {
                const float p0 = pt[(d + 0) * 64 + lane];
                const float p1 = pt[(d + 1) * 64 + lane];
                const float p2 = pt[(d + 2) * 64 + lane];
                const float p3 = pt[(d + 3) * 64 + lane];
#pragma unroll
                for (int i = 0; i < 8; ++i) {
                    const float4 kv = *reinterpret_cast<const float4*>(&ks[(g + 4 * i) * 64 + d]);
                    acc[i] = fmaf(kv.x, p0, fmaf(kv.y, p1, fmaf(kv.z, p2, fmaf(kv.w, p3, acc[i]))));
                }
            }
#pragma unroll
            for (int i = 0; i < 8; ++i) {
                const int r = g + 4 * i;
                float v = __expf(SCALE * acc[i]) + EPSF;
                if (n0 + r >= NN) v = 0.f;   // invalid rows contribute nothing
                kp[r * 64 + lane] = v;
            }
        }
        __syncthreads();

        // KV[m][d] += Kp[r][m] * V[r][d]; thread owns m = g*16+i (i<16), d = lane
        for (int r = 0; r < CH; ++r) {
            const float vv = vs[r * 64 + lane];
            const float4 k0 = *reinterpret_cast<const float4*>(&kp[r * 64 + g * 16 + 0]);
            const float4 k1 = *reinterpret_cast<const float4*>(&kp[r * 64 + g * 16 + 4]);
            const float4 k2 = *reinterpret_cast<const float4*>(&kp[r * 64 + g * 16 + 8]);
            const float4 k3 = *reinterpret_cast<const float4*>(&kp[r * 64 + g * 16 + 12]);
            accKV[0]  = fmaf(k0.x, vv, accKV[0]);
            accKV[1]  = fmaf(k0.y, vv, accKV[1]);
            accKV[2]  = fmaf(k0.z, vv, accKV[2]);
            accKV[3]  = fmaf(k0.w, vv, accKV[3]);
            accKV[4]  = fmaf(k1.x, vv, accKV[4]);
            accKV[5]  = fmaf(k1.y, vv, accKV[5]);
            accKV[6]  = fmaf(k1.z, vv, accKV[6]);
            accKV[7]  = fmaf(k1.w, vv, accKV[7]);
            accKV[8]  = fmaf(k2.x, vv, accKV[8]);
            accKV[9]  = fmaf(k2.y, vv, accKV[9]);
            accKV[10] = fmaf(k2.z, vv, accKV[10]);
            accKV[11] = fmaf(k2.w, vv, accKV[11]);
            accKV[12] = fmaf(k3.x, vv, accKV[12]);
            accKV[13] = fmaf(k3.y, vv, accKV[13]);
            accKV[14] = fmaf(k3.z, vv, accKV[14]);
            accKV[15] = fmaf(k3.w, vv, accKV[15]);
        }
        // Kp partial column sums: wave g sums its own 8 rows at m = lane
#pragma unroll
        for (int i = 0; i < 8; ++i) accSum += kp[(g + 4 * i) * 64 + lane];
    }

    // write this block's partial KV (deterministic layout [h][bx][m*64+d])
    float* dst = pKV + ((size_t)h * NSLICE + bx) * 4096;
#pragma unroll
    for (int i = 0; i < 16; ++i) dst[(g * 16 + i) * 64 + lane] = accKV[i];

    // reduce the 4 per-wave Kp sums through LDS (reuse kp)
    __syncthreads();
    kp[g * 64 + lane] = accSum;
    __syncthreads();
    if (g == 0)
        pSum[((size_t)h * NSLICE + bx) * 64 + lane] =
            kp[lane] + kp[64 + lane] + kp[128 + lane] + kp[192 + lane];
}

__global__ void reduce_kernel(const float* __restrict__ pKV, const float* __restrict__ pSum,
                              float* __restrict__ KV, float* __restrict__ Ksum)
{
    const int idx = blockIdx.x * 256 + threadIdx.x;
    if (idx < HH * 4096) {
        const int h  = idx >> 12;
        const int md = idx & 4095;
        float s = 0.f;
        for (int b = 0; b < NSLICE; ++b) s += pKV[((size_t)h * NSLICE + b) * 4096 + md];
        KV[idx] = s;
    } else {
        const int j = idx - HH * 4096;
        if (j < HH * 64) {
            const int h = j >> 6, m = j & 63;
            float s = 0.f;
            for (int b = 0; b < NSLICE; ++b) s += pSum[((size_t)h * NSLICE + b) * 64 + m];
            Ksum[j] = s;
        }
    }
}

__global__ __launch_bounds__(256)
void out_kernel(const float* __restrict__ x,
                const float* __restrict__ Wq, const float* __restrict__ bq,
                const float* __restrict__ proj,
                const float* __restrict__ KV, const float* __restrict__ Ksum,
                const float* __restrict__ Wo, const float* __restrict__ bo,
                float* __restrict__ out)
{
    __shared__ __align__(16) float xs[CH * C_IN];   // 32 KB
    __shared__ __align__(16) float pt[64 * 64];     // 16 KB
    __shared__ __align__(16) float qs[CH * 64];     // 8 KB (Q -> Qp -> Z, serially)
    __shared__ __align__(16) float kvs[64 * 64];    // 16 KB
    __shared__ __align__(16) float ksh[HH * 64];    // 2 KB  -> 74.25 KB, 2 blocks/CU

    const int t    = threadIdx.x;
    const int lane = t & 63;
    const int g    = t >> 6;
    const int n0   = blockIdx.x * CH;

    for (int idx = t; idx < 64 * 64; idx += 256)
        pt[(idx & 63) * 64 + (idx >> 6)] = proj[idx];
    for (int i4 = t; i4 < CH * 64; i4 += 256) {
        const int r = i4 >> 6;
        const int n = n0 + r;
        float4 v = make_float4(0.f, 0.f, 0.f, 0.f);
        if (n < NN) v = reinterpret_cast<const float4*>(x)[(size_t)n * 64 + (i4 & 63)];
        reinterpret_cast<float4*>(xs)[i4] = v;
    }
    ksh[t] = Ksum[t];
    ksh[t + 256] = Ksum[t + 256];

    const float boc = bo[lane];
    float accO[8];
#pragma unroll
    for (int i = 0; i < 8; ++i) accO[i] = boc;
    __syncthreads();

    for (int hp = 0; hp < HH; hp += 2) {
        // dual-head Q GEMM: amortize xs LDS reads over 2 heads
        const int   colA = hp * 64 + lane;
        const int   colB = colA + 64;
        float accQA[8], accQB[8];
        {
            const float ba = bq[colA], bb = bq[colB];
#pragma unroll
            for (int i = 0; i < 8; ++i) { accQA[i] = ba; accQB[i] = bb; }
        }
        for (int c = 0; c < C_IN; c += 4) {
            const float wa0 = Wq[(c + 0) * HDIM + colA];
            const float wa1 = Wq[(c + 1) * HDIM + colA];
            const float wa2 = Wq[(c + 2) * HDIM + colA];
            const float wa3 = Wq[(c + 3) * HDIM + colA];
            const float wb0 = Wq[(c + 0) * HDIM + colB];
            const float wb1 = Wq[(c + 1) * HDIM + colB];
            const float wb2 = Wq[(c + 2) * HDIM + colB];
            const float wb3 = Wq[(c + 3) * HDIM + colB];
#pragma unroll
            for (int i = 0; i < 8; ++i) {
                const float4 xv = *reinterpret_cast<const float4*>(&xs[(g + 4 * i) * C_IN + c]);
                accQA[i] = fmaf(xv.x, wa0, fmaf(xv.y, wa1, fmaf(xv.z, wa2, fmaf(xv.w, wa3, accQA[i]))));
                accQB[i] = fmaf(xv.x, wb0, fmaf(xv.y, wb1, fmaf(xv.z, wb2, fmaf(xv.w, wb3, accQB[i]))));
            }
        }

#pragma unroll
        for (int sub = 0; sub < 2; ++sub) {
            const int h = hp + sub;
            __syncthreads();                         // A: prev phase's qs/kvs readers done
#pragma unroll
            for (int i = 0; i < 8; ++i)
                qs[(g + 4 * i) * 64 + lane] = sub ? accQB[i] : accQA[i];
            for (int i4 = t; i4 < 1024; i4 += 256)   // stage this head's KV
                reinterpret_cast<float4*>(kvs)[i4] =
                    reinterpret_cast<const float4*>(KV)[h * 1024 + i4];
            __syncthreads();                         // B

            // Qp = exp(SCALE * Q . proj[m]) + eps
            float accP[8];
#pragma unroll
            for (int i = 0; i < 8; ++i) accP[i] = 0.f;
            for (int d = 0; d < 64; d += 4) {
                const float p0 = pt[(d + 0) * 64 + lane];
                const float p1 = pt[(d + 1) * 64 + lane];
                const float p2 = pt[(d + 2) * 64 + lane];
                const float p3 = pt[(d + 3) * 64 + lane];
#pragma unroll
                for (int i = 0; i < 8; ++i) {
                    const float4 qv = *reinterpret_cast<const float4*>(&qs[(g + 4 * i) * 64 + d]);
                    accP[i] = fmaf(qv.x, p0, fmaf(qv.y, p1, fmaf(qv.z, p2, fmaf(qv.w, p3, accP[i]))));
                }
            }
            __syncthreads();                         // C: qs reads done
#pragma unroll
            for (int i = 0; i < 8; ++i)
                qs[(g + 4 * i) * 64 + lane] = __expf(SCALE * accP[i]) + EPSF;
            __syncthreads();                         // D

            // Z = (Qp @ KV) / (Qp . Ksum + eps)
            float num[8], den[8];
#pragma unroll
            for (int i = 0; i < 8; ++i) { num[i] = 0.f; den[i] = 0.f; }
            for (int m = 0; m < 64; m += 4) {
                const float kv0 = kvs[(m + 0) * 64 + lane];
                const float kv1 = kvs[(m + 1) * 64 + lane];
                const float kv2 = kvs[(m + 2) * 64 + lane];
                const float kv3 = kvs[(m + 3) * 64 + lane];
                const float s0 = ksh[h * 64 + m + 0];
                const float s1 = ksh[h * 64 + m + 1];
                const float s2 = ksh[h * 64 + m + 2];
                const float s3 = ksh[h * 64 + m + 3];
#pragma unroll
                for (int i = 0; i < 8; ++i) {
                    const float4 q4 = *reinterpret_cast<const float4*>(&qs[(g + 4 * i) * 64 + m]);
                    num[i] = fmaf(q4.x, kv0, fmaf(q4.y, kv1, fmaf(q4.z, kv2, fmaf(q4.w, kv3, num[i]))));
                    den[i] = fmaf(q4.x, s0, fmaf(q4.y, s1, fmaf(q4.z, s2, fmaf(q4.w, s3, den[i]))));
                }
            }
            __syncthreads();                         // E
#pragma unroll
            for (int i = 0; i < 8; ++i)
                qs[(g + 4 * i) * 64 + lane] = num[i] / (den[i] + EPSF);
            __syncthreads();                         // F

            // out += Z_h @ Wo[h*64 : h*64+64, :]
            for (int d = 0; d < 64; d += 4) {
                const float w0 = Wo[(h * 64 + d + 0) * DD + lane];
                const float w1 = Wo[(h * 64 + d + 1) * DD + lane];
                const float w2 = Wo[(h * 64 + d + 2) * DD + lane];
                const float w3 = Wo[(h * 64 + d + 3) * DD + lane];
#pragma unroll
                for (int i = 0; i < 8; ++i) {
                    const float4 zv = *reinterpret_cast<const float4*>(&qs[(g + 4 * i) * 64 + d]);
                    accO[i] = fmaf(zv.x, w0, fmaf(zv.y, w1, fmaf(zv.z, w2, fmaf(zv.w, w3, accO[i]))));
                }
            }
        }
    }

#pragma unroll
    for (int i = 0; i < 8; ++i) {
        const int n = n0 + g + 4 * i;
        if (n < NN) out[(size_t)n * DD + lane] = accO[i];
    }
}

extern "C" void kernel_launch(void* const* d_in, const int* in_sizes, int n_in,
                              void* d_out, int out_size, void* d_ws, size_t ws_size,
                              hipStream_t stream) {
    const float* x    = (const float*)d_in[0];
    const float* Wq   = (const float*)d_in[1];
    const float* bq   = (const float*)d_in[2];
    const float* Wk   = (const float*)d_in[3];
    const float* bk   = (const float*)d_in[4];
    const float* Wv   = (const float*)d_in[5];
    const float* bv   = (const float*)d_in[6];
    const float* Wo   = (const float*)d_in[7];
    const float* bo   = (const float*)d_in[8];
    const float* proj = (const float*)d_in[9];
    float* out = (float*)d_out;

    // workspace (floats): pKV [8][64][4096], pSum [8][64][64], KV [8][4096], Ksum [8][64]
    float* ws   = (float*)d_ws;
    float* pKV  = ws;
    float* pSum = pKV  + (size_t)HH * NSLICE * 4096;  // +2,097,152
    float* KV   = pSum + (size_t)HH * NSLICE * 64;    // +32,768
    float* Ksum = KV   + (size_t)HH * 4096;           // +32,768  (~8.7 MB total)

    kv_partial_kernel<<<dim3(NSLICE, HH), 256, 0, stream>>>(x, Wk, bk, Wv, bv, proj, pKV, pSum);
    reduce_kernel<<<dim3(130), 256, 0, stream>>>(pKV, pSum, KV, Ksum);
    out_kernel<<<dim3(NCHUNK), 256, 0, stream>>>(x, Wq, bq, proj, KV, Ksum, Wo, bo, out);
}

// Round 3
// 333.354 us; speedup vs baseline: 7.7324x; 3.8639x over previous
//
#include <hip/hip_runtime.h>

// Performer attention (HyperGTConv): N=50000, C=256, H=8, D=M=64.
// Round 3: all GEMMs on bf16 MFMA (16x16x32), fp32 accumulation.
//   prep:   bf16 transposed weight copies (B-frags become contiguous 16B loads)
//   kv:     K,V = x@W -> Kp = exp(K@projT) -> KV += Kp^T@V, Ksum (partials)
//   reduce: partials -> KVT bf16 [h][d][m], Ksum fp32
//   out:    Q -> Qp -> Z = (Qp@KV)/(Qp.Ksum) -> out = Z@Wo + bo

#define NN      50000
#define C_IN    256
#define HH      8
#define DD      64
#define HDIM    512
#define EPSF    1e-6f
#define SCALE   0.044194173824159224f   // (1/sqrt(64)) * 64^(-1/4)
#define CH      64
#define NCHUNK  782                     // ceil(50000/64)
#define NSLICE  64
#define LDP     72                      // LDS row pitch (64 + 8 pad; 72*2B = 16B-mult)

typedef __bf16 bf16;
typedef __bf16 bf16x8 __attribute__((ext_vector_type(8)));
typedef float  f32x4  __attribute__((ext_vector_type(4)));

#define MFMA(a, b, c) __builtin_amdgcn_mfma_f32_16x16x32_bf16((a), (b), (c), 0, 0, 0)

__device__ __forceinline__ bf16x8 load_x_frag(const float* __restrict__ xrow, int col) {
    const float4 a = *reinterpret_cast<const float4*>(xrow + col);
    const float4 b = *reinterpret_cast<const float4*>(xrow + col + 4);
    bf16x8 r;
    r[0] = (bf16)a.x; r[1] = (bf16)a.y; r[2] = (bf16)a.z; r[3] = (bf16)a.w;
    r[4] = (bf16)b.x; r[5] = (bf16)b.y; r[6] = (bf16)b.z; r[7] = (bf16)b.w;
    return r;
}

__device__ __forceinline__ bf16x8 zero_frag() {
    bf16x8 r;
#pragma unroll
    for (int j = 0; j < 8; ++j) r[j] = (bf16)0.0f;
    return r;
}

// ---------- prep: transposed bf16 weight copies ----------
__global__ void prep_kernel(const float* __restrict__ Wq, const float* __restrict__ Wk,
                            const float* __restrict__ Wv, const float* __restrict__ Wo,
                            const float* __restrict__ proj,
                            bf16* __restrict__ WqT, bf16* __restrict__ WkT,
                            bf16* __restrict__ WvT, bf16* __restrict__ WoT,
                            bf16* __restrict__ projb)
{
    const int t = blockIdx.x * 256 + threadIdx.x;
    if (t < HDIM * C_IN) {                       // W^T[col][c] = W[c][col]
        const int col = t >> 8, c = t & 255;
        WqT[t] = (bf16)Wq[c * HDIM + col];
        WkT[t] = (bf16)Wk[c * HDIM + col];
        WvT[t] = (bf16)Wv[c * HDIM + col];
    } else if (t < HDIM * C_IN + DD * HDIM) {    // Wo^T[j][d'] = Wo[d'][j]
        const int i = t - HDIM * C_IN;
        const int j = i >> 9, d = i & 511;
        WoT[i] = (bf16)Wo[d * DD + j];
    } else if (t < HDIM * C_IN + DD * HDIM + 64 * 64) {
        const int i = t - HDIM * C_IN - DD * HDIM;
        projb[i] = (bf16)proj[i];
    }
}

// ---------- kernel 1: K,V,Kp,KV partials ----------
__global__ __launch_bounds__(256)
void kv_kernel(const float* __restrict__ x,
               const bf16* __restrict__ WkT, const float* __restrict__ bk,
               const bf16* __restrict__ WvT, const float* __restrict__ bv,
               const bf16* __restrict__ projb,
               float* __restrict__ pKV, float* __restrict__ pSum)
{
    __shared__ bf16 kbuf[64 * LDP];    // K  [n][d]
    __shared__ bf16 vtbuf[64 * LDP];   // V^T [d][n]
    __shared__ bf16 kptbuf[64 * LDP];  // Kp^T [m][n]
    __shared__ bf16 pjbuf[64 * LDP];   // proj [m][d]
    __shared__ float sred[4 * 64];

    const int t  = threadIdx.x;
    const int w  = t >> 6;     // wave 0..3
    const int l  = t & 63;
    const int lr = l & 15;     // row/col within 16-tile
    const int lk = l >> 4;     // k-group 0..3
    const int h  = blockIdx.y;
    const int bx = blockIdx.x;

    for (int i = t; i < 64 * 64; i += 256)
        pjbuf[(i >> 6) * LDP + (i & 63)] = projb[i];

    float bkc[4], bvc[4];
#pragma unroll
    for (int ct = 0; ct < 4; ++ct) {
        bkc[ct] = bk[h * 64 + ct * 16 + lr];
        bvc[ct] = bv[h * 64 + ct * 16 + lr];
    }

    f32x4 kvacc[4];
#pragma unroll
    for (int dt = 0; dt < 4; ++dt) kvacc[dt] = (f32x4){0.f, 0.f, 0.f, 0.f};
    float ksum_acc[4] = {0.f, 0.f, 0.f, 0.f};

    for (int chunk = bx; chunk < NCHUNK; chunk += NSLICE) {
        const int n0 = chunk * CH;

        // x A-fragments (rows n0 + w*16 + lr), bf16-converted in registers
        bf16x8 xa[8];
        const int xrow_i = n0 + w * 16 + lr;
        if (xrow_i < NN) {
            const float* xr = x + (size_t)xrow_i * C_IN;
#pragma unroll
            for (int kk = 0; kk < 8; ++kk) xa[kk] = load_x_frag(xr, kk * 32 + lk * 8);
        } else {
#pragma unroll
            for (int kk = 0; kk < 8; ++kk) xa[kk] = zero_frag();
        }

        __syncthreads();   // previous iteration's buffer readers done

        // ---- K,V GEMM: C tiles rows 16w.., cols ct*16.. ----
        const int nrow = w * 16 + lk * 4;   // C-frag row base within chunk
#pragma unroll
        for (int ct = 0; ct < 4; ++ct) {
            f32x4 aK = (f32x4){bkc[ct], bkc[ct], bkc[ct], bkc[ct]};
            f32x4 aV = (f32x4){bvc[ct], bvc[ct], bvc[ct], bvc[ct]};
            const bf16* wkp = WkT + (size_t)(h * 64 + ct * 16 + lr) * C_IN + lk * 8;
            const bf16* wvp = WvT + (size_t)(h * 64 + ct * 16 + lr) * C_IN + lk * 8;
#pragma unroll
            for (int kk = 0; kk < 8; ++kk) {
                aK = MFMA(xa[kk], *reinterpret_cast<const bf16x8*>(wkp + kk * 32), aK);
                aV = MFMA(xa[kk], *reinterpret_cast<const bf16x8*>(wvp + kk * 32), aV);
            }
            const int dcol = ct * 16 + lr;
#pragma unroll
            for (int r = 0; r < 4; ++r) {
                kbuf[(nrow + r) * LDP + dcol] = (bf16)aK[r];
                // zero invalid V rows so KV = Kp^T V stays clean
                vtbuf[dcol * LDP + (nrow + r)] =
                    (n0 + nrow + r < NN) ? (bf16)aV[r] : (bf16)0.0f;
            }
        }
        __syncthreads();

        // ---- Kfeat = K @ proj^T, exp -> Kp^T ----
        bf16x8 ka[2];
#pragma unroll
        for (int kk = 0; kk < 2; ++kk)
            ka[kk] = *reinterpret_cast<const bf16x8*>(
                &kbuf[(w * 16 + lr) * LDP + kk * 32 + lk * 8]);
#pragma unroll
        for (int mt = 0; mt < 4; ++mt) {
            f32x4 acc = (f32x4){0.f, 0.f, 0.f, 0.f};
#pragma unroll
            for (int kk = 0; kk < 2; ++kk)
                acc = MFMA(ka[kk], *reinterpret_cast<const bf16x8*>(
                               &pjbuf[(mt * 16 + lr) * LDP + kk * 32 + lk * 8]), acc);
#pragma unroll
            for (int r = 0; r < 4; ++r) {
                const float kp = (n0 + nrow + r < NN)
                                     ? (__expf(SCALE * acc[r]) + EPSF) : 0.0f;
                ksum_acc[mt] += kp;
                kptbuf[(mt * 16 + lr) * LDP + (nrow + r)] = (bf16)kp;
            }
        }
        __syncthreads();

        // ---- KV += Kp^T @ V : wave owns m-strip 16w, 4 d-tiles ----
        bf16x8 kpa[2];
#pragma unroll
        for (int kk = 0; kk < 2; ++kk)
            kpa[kk] = *reinterpret_cast<const bf16x8*>(
                &kptbuf[(w * 16 + lr) * LDP + kk * 32 + lk * 8]);
#pragma unroll
        for (int dt = 0; dt < 4; ++dt) {
#pragma unroll
            for (int kk = 0; kk < 2; ++kk)
                kvacc[dt] = MFMA(kpa[kk], *reinterpret_cast<const bf16x8*>(
                                     &vtbuf[(dt * 16 + lr) * LDP + kk * 32 + lk * 8]),
                                 kvacc[dt]);
        }
    }

    // partial KV write: m = 16w + lk*4 + r, d = dt*16 + lr
    float* dst = pKV + ((size_t)h * NSLICE + bx) * 4096;
#pragma unroll
    for (int dt = 0; dt < 4; ++dt)
#pragma unroll
        for (int r = 0; r < 4; ++r)
            dst[(w * 16 + lk * 4 + r) * 64 + dt * 16 + lr] = kvacc[dt][r];

    // Ksum partial: reduce across lk groups then across waves
#pragma unroll
    for (int mt = 0; mt < 4; ++mt) {
        float s = ksum_acc[mt];
        s += __shfl_xor(s, 16, 64);
        s += __shfl_xor(s, 32, 64);
        if (lk == 0) sred[w * 64 + mt * 16 + lr] = s;
    }
    __syncthreads();
    if (t < 64)
        pSum[((size_t)h * NSLICE + bx) * 64 + t] =
            sred[t] + sred[64 + t] + sred[128 + t] + sred[192 + t];
}

// ---------- reduce: partials -> KVT bf16 + Ksum ----------
__global__ void reduce_kernel(const float* __restrict__ pKV, const float* __restrict__ pSum,
                              bf16* __restrict__ KVT, float* __restrict__ Ksum)
{
    const int idx = blockIdx.x * 256 + threadIdx.x;
    if (idx < HH * 4096) {
        const int h = idx >> 12, md = idx & 4095;
        const int m = md >> 6, d = md & 63;
        float s = 0.f;
        for (int b = 0; b < NSLICE; ++b) s += pKV[((size_t)h * NSLICE + b) * 4096 + md];
        KVT[h * 4096 + d * 64 + m] = (bf16)s;     // transposed for B-frag reads
    } else if (idx < HH * 4096 + HH * 64) {
        const int j = idx - HH * 4096;
        const int h = j >> 6, m = j & 63;
        float s = 0.f;
        for (int b = 0; b < NSLICE; ++b) s += pSum[((size_t)h * NSLICE + b) * 64 + m];
        Ksum[j] = s;
    }
}

// ---------- kernel 3: Q -> Qp -> Z -> out ----------
__global__ __launch_bounds__(256)
void out_kernel(const float* __restrict__ x,
                const bf16* __restrict__ WqT, const float* __restrict__ bq,
                const bf16* __restrict__ projb,
                const bf16* __restrict__ KVT, const float* __restrict__ Ksum,
                const bf16* __restrict__ WoT, const float* __restrict__ bo,
                float* __restrict__ out)
{
    __shared__ bf16 qbuf[64 * LDP];
    __shared__ bf16 qpbuf[64 * LDP];
    __shared__ bf16 zbuf[64 * LDP];
    __shared__ bf16 pjbuf[64 * LDP];

    const int t  = threadIdx.x;
    const int w  = t >> 6;
    const int l  = t & 63;
    const int lr = l & 15;
    const int lk = l >> 4;
    const int n0 = blockIdx.x * CH;

    for (int i = t; i < 64 * 64; i += 256)
        pjbuf[(i >> 6) * LDP + (i & 63)] = projb[i];

    bf16x8 xa[8];
    const int xrow_i = n0 + w * 16 + lr;
    if (xrow_i < NN) {
        const float* xr = x + (size_t)xrow_i * C_IN;
#pragma unroll
        for (int kk = 0; kk < 8; ++kk) xa[kk] = load_x_frag(xr, kk * 32 + lk * 8);
    } else {
#pragma unroll
        for (int kk = 0; kk < 8; ++kk) xa[kk] = zero_frag();
    }

    f32x4 oacc[4];
#pragma unroll
    for (int jt = 0; jt < 4; ++jt) {
        const float b = bo[jt * 16 + lr];
        oacc[jt] = (f32x4){b, b, b, b};
    }

    const int nrow = w * 16 + lk * 4;
    __syncthreads();   // pjbuf ready

    for (int h = 0; h < HH; ++h) {
        // ---- Q GEMM ----
#pragma unroll
        for (int ct = 0; ct < 4; ++ct) {
            const float bqc = bq[h * 64 + ct * 16 + lr];
            f32x4 aQ = (f32x4){bqc, bqc, bqc, bqc};
            const bf16* wqp = WqT + (size_t)(h * 64 + ct * 16 + lr) * C_IN + lk * 8;
#pragma unroll
            for (int kk = 0; kk < 8; ++kk)
                aQ = MFMA(xa[kk], *reinterpret_cast<const bf16x8*>(wqp + kk * 32), aQ);
#pragma unroll
            for (int r = 0; r < 4; ++r)
                qbuf[(nrow + r) * LDP + ct * 16 + lr] = (bf16)aQ[r];
        }
        __syncthreads();

        // ---- Qp = exp(SCALE * Q@proj^T) + eps; den partials ----
        bf16x8 qa[2];
#pragma unroll
        for (int kk = 0; kk < 2; ++kk)
            qa[kk] = *reinterpret_cast<const bf16x8*>(
                &qbuf[(w * 16 + lr) * LDP + kk * 32 + lk * 8]);
        float denp[4] = {0.f, 0.f, 0.f, 0.f};
#pragma unroll
        for (int mt = 0; mt < 4; ++mt) {
            f32x4 acc = (f32x4){0.f, 0.f, 0.f, 0.f};
#pragma unroll
            for (int kk = 0; kk < 2; ++kk)
                acc = MFMA(qa[kk], *reinterpret_cast<const bf16x8*>(
                               &pjbuf[(mt * 16 + lr) * LDP + kk * 32 + lk * 8]), acc);
            const float ks = Ksum[h * 64 + mt * 16 + lr];
#pragma unroll
            for (int r = 0; r < 4; ++r) {
                const float qp = __expf(SCALE * acc[r]) + EPSF;
                denp[r] += qp * ks;
                qpbuf[(nrow + r) * LDP + mt * 16 + lr] = (bf16)qp;
            }
        }
        // reduce den over the 16 m-lanes (bits 0-3 of lane id)
#pragma unroll
        for (int r = 0; r < 4; ++r) {
            denp[r] += __shfl_xor(denp[r], 1, 64);
            denp[r] += __shfl_xor(denp[r], 2, 64);
            denp[r] += __shfl_xor(denp[r], 4, 64);
            denp[r] += __shfl_xor(denp[r], 8, 64);
        }
        __syncthreads();

        // ---- Z = (Qp @ KV) / (den + eps) ----
        bf16x8 qpa[2];
#pragma unroll
        for (int kk = 0; kk < 2; ++kk)
            qpa[kk] = *reinterpret_cast<const bf16x8*>(
                &qpbuf[(w * 16 + lr) * LDP + kk * 32 + lk * 8]);
#pragma unroll
        for (int dt = 0; dt < 4; ++dt) {
            f32x4 num = (f32x4){0.f, 0.f, 0.f, 0.f};
            const bf16* kvp = KVT + h * 4096 + (dt * 16 + lr) * 64 + lk * 8;
#pragma unroll
            for (int kk = 0; kk < 2; ++kk)
                num = MFMA(qpa[kk], *reinterpret_cast<const bf16x8*>(kvp + kk * 32), num);
#pragma unroll
            for (int r = 0; r < 4; ++r)
                zbuf[(nrow + r) * LDP + dt * 16 + lr] = (bf16)(num[r] / (denp[r] + EPSF));
        }
        __syncthreads();

        // ---- out += Z @ Wo_h ----
        bf16x8 za[2];
#pragma unroll
        for (int kk = 0; kk < 2; ++kk)
            za[kk] = *reinterpret_cast<const bf16x8*>(
                &zbuf[(w * 16 + lr) * LDP + kk * 32 + lk * 8]);
#pragma unroll
        for (int jt = 0; jt < 4; ++jt) {
            const bf16* wop = WoT + (size_t)(jt * 16 + lr) * HDIM + h * 64 + lk * 8;
#pragma unroll
            for (int kk = 0; kk < 2; ++kk)
                oacc[jt] = MFMA(za[kk], *reinterpret_cast<const bf16x8*>(wop + kk * 32),
                                oacc[jt]);
        }
        __syncthreads();   // separates za reads from next head's buffer writes
    }

#pragma unroll
    for (int jt = 0; jt < 4; ++jt)
#pragma unroll
        for (int r = 0; r < 4; ++r) {
            const int n = n0 + nrow + r;
            if (n < NN) out[(size_t)n * DD + jt * 16 + lr] = oacc[jt][r];
        }
}

extern "C" void kernel_launch(void* const* d_in, const int* in_sizes, int n_in,
                              void* d_out, int out_size, void* d_ws, size_t ws_size,
                              hipStream_t stream) {
    const float* x    = (const float*)d_in[0];
    const float* Wq   = (const float*)d_in[1];
    const float* bq   = (const float*)d_in[2];
    const float* Wk   = (const float*)d_in[3];
    const float* bk   = (const float*)d_in[4];
    const float* Wv   = (const float*)d_in[5];
    const float* bv   = (const float*)d_in[6];
    const float* Wo   = (const float*)d_in[7];
    const float* bo   = (const float*)d_in[8];
    const float* proj = (const float*)d_in[9];
    float* out = (float*)d_out;

    // workspace layout (bytes), fp32 first then bf16 (all offsets 2KB-aligned):
    char* ws = (char*)d_ws;
    float* pKV  = (float*)ws;                                    // 8*64*4096*4 = 8388608
    float* pSum = (float*)(ws + 8388608);                        // 8*64*64*4   = 131072
    float* Ksum = (float*)(ws + 8388608 + 131072);               // 8*64*4      = 2048
    bf16*  WqT  = (bf16*)(ws + 8388608 + 131072 + 2048);         // 512*256*2   = 262144
    bf16*  WkT  = WqT + HDIM * C_IN;
    bf16*  WvT  = WkT + HDIM * C_IN;
    bf16*  WoT  = WvT + HDIM * C_IN;                             // 64*512*2    = 65536
    bf16*  projb= WoT + DD * HDIM;                               // 64*64*2     = 8192
    bf16*  KVT  = projb + 64 * 64;                               // 8*4096*2    = 65536
    // total ~9.4 MB

    prep_kernel<<<dim3(656), 256, 0, stream>>>(Wq, Wk, Wv, Wo, proj,
                                               WqT, WkT, WvT, WoT, projb);
    kv_kernel<<<dim3(NSLICE, HH), 256, 0, stream>>>(x, WkT, bk, WvT, bv, projb,
                                                    pKV, pSum);
    reduce_kernel<<<dim3(130), 256, 0, stream>>>(pKV, pSum, KVT, Ksum);
    out_kernel<<<dim3(NCHUNK), 256, 0, stream>>>(x, WqT, bq, projb, KVT, Ksum,
                                                 WoT, bo, out);
}

// Round 4
// 315.678 us; speedup vs baseline: 8.1653x; 1.0560x over previous
//
#include <hip/hip_runtime.h>

// Performer attention (HyperGTConv): N=50000, C=256, H=8, D=M=64.
// Round 4: barrier-free per-wave MFMA chains.
//  - proj folded into weights: Wqp = Wq@projT, Wkp = Wk@projT (prep, fp32->bf16)
//  - each wave owns 32 rows; all transposes via per-wave LDS + lgkmcnt fences
//  - zero __syncthreads in main loops; kv block-reduces partials in epilogue
//  - __launch_bounds__(256,2) so the compiler may use up to 256 VGPRs

#define NN      50000
#define HDIM    512
#define EPSF    1e-6f
#define SCALE   0.044194173824159224f   // (1/sqrt(64)) * 64^(-1/4)
#define NCH128  391                     // ceil(50000/128)
#define NSLICE  64                      // kv blocks per head
#define LDPA    72                      // [32][72] bf16: row-major strip buf
#define LDPB    40                      // [64][40] bf16: transposed strip buf

typedef __bf16 bf16;
typedef __bf16 bf16x8 __attribute__((ext_vector_type(8)));
typedef float  f32x4  __attribute__((ext_vector_type(4)));

#define MFMA(a, b, c) __builtin_amdgcn_mfma_f32_16x16x32_bf16((a), (b), (c), 0, 0, 0)

__device__ __forceinline__ void lds_fence() {
    asm volatile("s_waitcnt lgkmcnt(0)" ::: "memory");
}

__device__ __forceinline__ bf16x8 load_x_frag(const float* __restrict__ xrow, int col) {
    const float4 a = *reinterpret_cast<const float4*>(xrow + col);
    const float4 b = *reinterpret_cast<const float4*>(xrow + col + 4);
    bf16x8 r;
    r[0] = (bf16)a.x; r[1] = (bf16)a.y; r[2] = (bf16)a.z; r[3] = (bf16)a.w;
    r[4] = (bf16)b.x; r[5] = (bf16)b.y; r[6] = (bf16)b.z; r[7] = (bf16)b.w;
    return r;
}

// ---------- prep: folded + transposed bf16 weights ----------
__global__ void prep_kernel(const float* __restrict__ Wq, const float* __restrict__ bq,
                            const float* __restrict__ Wk, const float* __restrict__ bk,
                            const float* __restrict__ Wv, const float* __restrict__ Wo,
                            const float* __restrict__ proj,
                            bf16* __restrict__ WqpT, bf16* __restrict__ WkpT,
                            bf16* __restrict__ WvT, bf16* __restrict__ WoT,
                            float* __restrict__ fqb, float* __restrict__ fkb)
{
    const int t = blockIdx.x * 256 + threadIdx.x;
    if (t < 131072) {                       // WqpT/WkpT [h*64+m][c] = sum_d W[c][h,d] proj[m][d]
        const int row = t >> 8, c = t & 255;
        const int hh = row >> 6, m = row & 63;
        const float* pr = proj + m * 64;
        const float* wq = Wq + (size_t)c * HDIM + hh * 64;
        const float* wk = Wk + (size_t)c * HDIM + hh * 64;
        float sq = 0.f, sk = 0.f;
        for (int d = 0; d < 64; ++d) { const float p = pr[d]; sq += wq[d] * p; sk += wk[d] * p; }
        WqpT[(size_t)row * 256 + c] = (bf16)sq;
        WkpT[(size_t)row * 256 + c] = (bf16)sk;
    } else if (t < 262144) {                // WvT[col][c] = Wv[c][col]
        const int i = t - 131072;
        const int col = i >> 8, c = i & 255;
        WvT[i] = (bf16)Wv[(size_t)c * HDIM + col];
    } else if (t < 262144 + 32768) {        // WoT[j][dp] = Wo[dp][j]
        const int i = t - 262144;
        const int j = i >> 9, dp = i & 511;
        WoT[i] = (bf16)Wo[(size_t)dp * 64 + j];
    } else if (t < 262144 + 32768 + 1024) { // fqb/fkb[h*64+m] = sum_d b[h,d] proj[m][d]
        const int i = t - 262144 - 32768;
        const int which = i >> 9, row = i & 511;
        const int hh = row >> 6, m = row & 63;
        const float* pr = proj + m * 64;
        const float* b = (which ? bk : bq) + hh * 64;
        float s = 0.f;
        for (int d = 0; d < 64; ++d) s += b[d] * pr[d];
        (which ? fkb : fqb)[row] = s;
    }
}

// ---------- kernel 1: Kp, V, KV partials (barrier-free main loop) ----------
__global__ __launch_bounds__(256, 2)
void kv_kernel(const float* __restrict__ x,
               const bf16* __restrict__ WkpT, const float* __restrict__ fkb,
               const bf16* __restrict__ WvT,  const float* __restrict__ bv,
               float* __restrict__ pKV, float* __restrict__ pSum)
{
    __shared__ __align__(16) char pool[4 * 2 * 64 * LDPB * 2];   // 40960 B
    const int t  = threadIdx.x;
    const int w  = t >> 6;
    const int l  = t & 63;
    const int lr = l & 15;
    const int lk = l >> 4;
    const int h  = blockIdx.y;
    const int bx = blockIdx.x;

    bf16* kptbuf = (bf16*)(pool + w * (2 * 64 * LDPB * 2));   // [64 m][40 n]
    bf16* vtbuf  = kptbuf + 64 * LDPB;                        // [64 d][40 n]

    f32x4 kvacc[16];
#pragma unroll
    for (int i = 0; i < 16; ++i) kvacc[i] = (f32x4){0.f, 0.f, 0.f, 0.f};
    float ksum_acc[4] = {0.f, 0.f, 0.f, 0.f};

    float fkbc[4], bvc[4];
#pragma unroll
    for (int q = 0; q < 4; ++q) {
        fkbc[q] = fkb[h * 64 + q * 16 + lr];
        bvc[q]  = bv [h * 64 + q * 16 + lr];
    }

    for (int chunk = bx; chunk < NCH128; chunk += NSLICE) {
        const int nbase = chunk * 128 + w * 32;
        const float* xr0 = x + (size_t)min(nbase + lr,      NN - 1) * 256;
        const float* xr1 = x + (size_t)min(nbase + 16 + lr, NN - 1) * 256;

        // ---- Kfeat = x@Wkp + fkb ; V = x@Wv + bv  (single pass over k) ----
        f32x4 fK[2][4], aV[2][4];
#pragma unroll
        for (int q = 0; q < 4; ++q) {
            fK[0][q] = (f32x4){fkbc[q], fkbc[q], fkbc[q], fkbc[q]};
            fK[1][q] = fK[0][q];
            aV[0][q] = (f32x4){bvc[q], bvc[q], bvc[q], bvc[q]};
            aV[1][q] = aV[0][q];
        }
#pragma unroll
        for (int kk = 0; kk < 8; ++kk) {
            const bf16x8 xa0 = load_x_frag(xr0, kk * 32 + lk * 8);
            const bf16x8 xa1 = load_x_frag(xr1, kk * 32 + lk * 8);
#pragma unroll
            for (int mt = 0; mt < 4; ++mt) {
                const bf16x8 wb = *reinterpret_cast<const bf16x8*>(
                    &WkpT[(size_t)(h * 64 + mt * 16 + lr) * 256 + kk * 32 + lk * 8]);
                fK[0][mt] = MFMA(xa0, wb, fK[0][mt]);
                fK[1][mt] = MFMA(xa1, wb, fK[1][mt]);
            }
#pragma unroll
            for (int ct = 0; ct < 4; ++ct) {
                const bf16x8 wb = *reinterpret_cast<const bf16x8*>(
                    &WvT[(size_t)(h * 64 + ct * 16 + lr) * 256 + kk * 32 + lk * 8]);
                aV[0][ct] = MFMA(xa0, wb, aV[0][ct]);
                aV[1][ct] = MFMA(xa1, wb, aV[1][ct]);
            }
        }

        lds_fence();   // previous iteration's kpa/vb reads drained
        // ---- exp -> Kp^T [m][n]; V^T [d][n]; zero invalid rows ----
#pragma unroll
        for (int rt = 0; rt < 2; ++rt)
#pragma unroll
            for (int q = 0; q < 4; ++q)
#pragma unroll
                for (int r = 0; r < 4; ++r) {
                    const int nl = rt * 16 + lk * 4 + r;
                    const bool valid = (nbase + nl) < NN;
                    const float kpv = valid ? (__expf(SCALE * fK[rt][q][r]) + EPSF) : 0.f;
                    ksum_acc[q] += kpv;
                    kptbuf[(q * 16 + lr) * LDPB + nl] = (bf16)kpv;
                    vtbuf [(q * 16 + lr) * LDPB + nl] = valid ? (bf16)aV[rt][q][r] : (bf16)0.f;
                }
        lds_fence();   // writes visible to whole wave

        // ---- KV += Kp^T @ V ----
        bf16x8 kpa[4], vb[4];
#pragma unroll
        for (int mt = 0; mt < 4; ++mt)
            kpa[mt] = *reinterpret_cast<const bf16x8*>(&kptbuf[(mt * 16 + lr) * LDPB + lk * 8]);
#pragma unroll
        for (int dt = 0; dt < 4; ++dt)
            vb[dt] = *reinterpret_cast<const bf16x8*>(&vtbuf[(dt * 16 + lr) * LDPB + lk * 8]);
#pragma unroll
        for (int mt = 0; mt < 4; ++mt)
#pragma unroll
            for (int dt = 0; dt < 4; ++dt)
                kvacc[mt * 4 + dt] = MFMA(kpa[mt], vb[dt], kvacc[mt * 4 + dt]);
    }

    // ---- epilogue: ksum shfl reduce; block-level KV reduce (2 steps) ----
#pragma unroll
    for (int q = 0; q < 4; ++q) {
        float s = ksum_acc[q];
        s += __shfl_xor(s, 16, 64);
        s += __shfl_xor(s, 32, 64);
        ksum_acc[q] = s;
    }

    float* red   = (float*)pool;            // 32768 B
    float* sredp = (float*)(pool + 33024);  // 1024 B (disjoint from red)

    __syncthreads();   // S1: all loop LDS traffic done
    if (lk == 0) {
#pragma unroll
        for (int q = 0; q < 4; ++q) sredp[w * 64 + q * 16 + lr] = ksum_acc[q];
    }
    if (w >= 2) {
#pragma unroll
        for (int mt = 0; mt < 4; ++mt)
#pragma unroll
            for (int dt = 0; dt < 4; ++dt)
#pragma unroll
                for (int r = 0; r < 4; ++r)
                    red[(w - 2) * 4096 + (mt * 16 + lk * 4 + r) * 64 + dt * 16 + lr] =
                        kvacc[mt * 4 + dt][r];
    }
    __syncthreads();   // S2
    if (w < 2) {
#pragma unroll
        for (int mt = 0; mt < 4; ++mt)
#pragma unroll
            for (int dt = 0; dt < 4; ++dt)
#pragma unroll
                for (int r = 0; r < 4; ++r)
                    kvacc[mt * 4 + dt][r] +=
                        red[w * 4096 + (mt * 16 + lk * 4 + r) * 64 + dt * 16 + lr];
    }
    __syncthreads();   // S3
    if (w == 1) {
#pragma unroll
        for (int mt = 0; mt < 4; ++mt)
#pragma unroll
            for (int dt = 0; dt < 4; ++dt)
#pragma unroll
                for (int r = 0; r < 4; ++r)
                    red[(mt * 16 + lk * 4 + r) * 64 + dt * 16 + lr] = kvacc[mt * 4 + dt][r];
    }
    __syncthreads();   // S4
    if (w == 0) {
        float* dst = pKV + ((size_t)h * NSLICE + bx) * 4096;
#pragma unroll
        for (int mt = 0; mt < 4; ++mt)
#pragma unroll
            for (int dt = 0; dt < 4; ++dt)
#pragma unroll
                for (int r = 0; r < 4; ++r) {
                    const int md = (mt * 16 + lk * 4 + r) * 64 + dt * 16 + lr;
                    dst[md] = kvacc[mt * 4 + dt][r] + red[md];
                }
    }
    if (t < 64)
        pSum[((size_t)h * NSLICE + bx) * 64 + t] =
            sredp[t] + sredp[64 + t] + sredp[128 + t] + sredp[192 + t];
}

// ---------- reduce: partials -> KVT bf16 [h][d][m] + Ksum fp32 ----------
__global__ void reduce_kernel(const float* __restrict__ pKV, const float* __restrict__ pSum,
                              bf16* __restrict__ KVT, float* __restrict__ Ksum)
{
    const int idx = blockIdx.x * 256 + threadIdx.x;
    if (idx < 8 * 4096) {
        const int h = idx >> 12, md = idx & 4095;
        const int m = md >> 6, d = md & 63;
        float s = 0.f;
        for (int b = 0; b < NSLICE; ++b) s += pKV[((size_t)h * NSLICE + b) * 4096 + md];
        KVT[h * 4096 + d * 64 + m] = (bf16)s;
    } else if (idx < 8 * 4096 + 512) {
        const int j = idx - 8 * 4096;
        const int h = j >> 6, m = j & 63;
        float s = 0.f;
        for (int b = 0; b < NSLICE; ++b) s += pSum[((size_t)h * NSLICE + b) * 64 + m];
        Ksum[j] = s;
    }
}

// ---------- kernel 3: Qp -> Z -> out (zero barriers) ----------
__global__ __launch_bounds__(256, 2)
void out_kernel(const float* __restrict__ x,
                const bf16* __restrict__ WqpT, const float* __restrict__ fqb,
                const bf16* __restrict__ KVT, const float* __restrict__ Ksum,
                const bf16* __restrict__ WoT, const float* __restrict__ bo,
                float* __restrict__ out)
{
    __shared__ __align__(16) bf16 tbufs[4][32 * LDPA];   // 4 x 4608 B
    const int t  = threadIdx.x;
    const int w  = t >> 6;
    const int l  = t & 63;
    const int lr = l & 15;
    const int lk = l >> 4;
    bf16* tbuf = tbufs[w];
    const int nbase = blockIdx.x * 128 + w * 32;

    const float* xr0 = x + (size_t)min(nbase + lr,      NN - 1) * 256;
    const float* xr1 = x + (size_t)min(nbase + 16 + lr, NN - 1) * 256;
    bf16x8 xa[2][8];
#pragma unroll
    for (int kk = 0; kk < 8; ++kk) {
        xa[0][kk] = load_x_frag(xr0, kk * 32 + lk * 8);
        xa[1][kk] = load_x_frag(xr1, kk * 32 + lk * 8);
    }

    f32x4 oacc[2][4];
#pragma unroll
    for (int jt = 0; jt < 4; ++jt) {
        const float b = bo[jt * 16 + lr];
        oacc[0][jt] = (f32x4){b, b, b, b};
        oacc[1][jt] = oacc[0][jt];
    }

    for (int h = 0; h < 8; ++h) {
        // ---- Qfeat = x@Wqp + fqb ----
        f32x4 fQ[2][4];
#pragma unroll
        for (int mt = 0; mt < 4; ++mt) {
            const float b = fqb[h * 64 + mt * 16 + lr];
            fQ[0][mt] = (f32x4){b, b, b, b};
            fQ[1][mt] = fQ[0][mt];
        }
#pragma unroll
        for (int kk = 0; kk < 8; ++kk) {
#pragma unroll
            for (int mt = 0; mt < 4; ++mt) {
                const bf16x8 wb = *reinterpret_cast<const bf16x8*>(
                    &WqpT[(size_t)(h * 64 + mt * 16 + lr) * 256 + kk * 32 + lk * 8]);
                fQ[0][mt] = MFMA(xa[0][kk], wb, fQ[0][mt]);
                fQ[1][mt] = MFMA(xa[1][kk], wb, fQ[1][mt]);
            }
        }

        // ---- qp = exp(SCALE*feat)+eps; den partials; write qp -> tbuf ----
        lds_fence();   // drain previous head's za reads
        float denp[2][4] = {{0.f,0.f,0.f,0.f},{0.f,0.f,0.f,0.f}};
#pragma unroll
        for (int rt = 0; rt < 2; ++rt)
#pragma unroll
            for (int mt = 0; mt < 4; ++mt) {
                const float ks = Ksum[h * 64 + mt * 16 + lr];
#pragma unroll
                for (int r = 0; r < 4; ++r) {
                    const float qp = __expf(SCALE * fQ[rt][mt][r]) + EPSF;
                    denp[rt][r] += qp * ks;
                    tbuf[(rt * 16 + lk * 4 + r) * LDPA + mt * 16 + lr] = (bf16)qp;
                }
            }
#pragma unroll
        for (int rt = 0; rt < 2; ++rt)
#pragma unroll
            for (int r = 0; r < 4; ++r) {
                float s = denp[rt][r];
                s += __shfl_xor(s, 1, 64);
                s += __shfl_xor(s, 2, 64);
                s += __shfl_xor(s, 4, 64);
                s += __shfl_xor(s, 8, 64);
                denp[rt][r] = s;
            }
        lds_fence();

        // ---- num = Qp @ KV ----
        bf16x8 qpa[2][2];
#pragma unroll
        for (int rt = 0; rt < 2; ++rt)
#pragma unroll
            for (int kk = 0; kk < 2; ++kk)
                qpa[rt][kk] = *reinterpret_cast<const bf16x8*>(
                    &tbuf[(rt * 16 + lr) * LDPA + kk * 32 + lk * 8]);
        f32x4 num[2][4];
#pragma unroll
        for (int dt = 0; dt < 4; ++dt) { num[0][dt] = (f32x4){0.f,0.f,0.f,0.f}; num[1][dt] = num[0][dt]; }
#pragma unroll
        for (int dt = 0; dt < 4; ++dt)
#pragma unroll
            for (int kk = 0; kk < 2; ++kk) {
                const bf16x8 kvb = *reinterpret_cast<const bf16x8*>(
                    &KVT[h * 4096 + (dt * 16 + lr) * 64 + kk * 32 + lk * 8]);
                num[0][dt] = MFMA(qpa[0][kk], kvb, num[0][dt]);
                num[1][dt] = MFMA(qpa[1][kk], kvb, num[1][dt]);
            }

        // ---- z = num/den -> tbuf ----
        lds_fence();   // drain qpa reads
#pragma unroll
        for (int rt = 0; rt < 2; ++rt)
#pragma unroll
            for (int dt = 0; dt < 4; ++dt)
#pragma unroll
                for (int r = 0; r < 4; ++r)
                    tbuf[(rt * 16 + lk * 4 + r) * LDPA + dt * 16 + lr] =
                        (bf16)(num[rt][dt][r] / (denp[rt][r] + EPSF));
        lds_fence();

        // ---- out += Z @ Wo_h ----
        bf16x8 za[2][2];
#pragma unroll
        for (int rt = 0; rt < 2; ++rt)
#pragma unroll
            for (int kk = 0; kk < 2; ++kk)
                za[rt][kk] = *reinterpret_cast<const bf16x8*>(
                    &tbuf[(rt * 16 + lr) * LDPA + kk * 32 + lk * 8]);
#pragma unroll
        for (int jt = 0; jt < 4; ++jt)
#pragma unroll
            for (int kk = 0; kk < 2; ++kk) {
                const bf16x8 wo = *reinterpret_cast<const bf16x8*>(
                    &WoT[(size_t)(jt * 16 + lr) * HDIM + h * 64 + kk * 32 + lk * 8]);
                oacc[0][jt] = MFMA(za[0][kk], wo, oacc[0][jt]);
                oacc[1][jt] = MFMA(za[1][kk], wo, oacc[1][jt]);
            }
    }

#pragma unroll
    for (int rt = 0; rt < 2; ++rt)
#pragma unroll
        for (int jt = 0; jt < 4; ++jt)
#pragma unroll
            for (int r = 0; r < 4; ++r) {
                const int n = nbase + rt * 16 + lk * 4 + r;
                if (n < NN) out[(size_t)n * 64 + jt * 16 + lr] = oacc[rt][jt][r];
            }
}

extern "C" void kernel_launch(void* const* d_in, const int* in_sizes, int n_in,
                              void* d_out, int out_size, void* d_ws, size_t ws_size,
                              hipStream_t stream) {
    const float* x    = (const float*)d_in[0];
    const float* Wq   = (const float*)d_in[1];
    const float* bq   = (const float*)d_in[2];
    const float* Wk   = (const float*)d_in[3];
    const float* bk   = (const float*)d_in[4];
    const float* Wv   = (const float*)d_in[5];
    const float* bv   = (const float*)d_in[6];
    const float* Wo   = (const float*)d_in[7];
    const float* bo   = (const float*)d_in[8];
    const float* proj = (const float*)d_in[9];
    float* out = (float*)d_out;

    // workspace layout (bytes)
    char* ws = (char*)d_ws;
    float* pKV  = (float*)ws;                         // 8*64*4096*4 = 8388608
    float* pSum = (float*)(ws + 8388608);             // 131072
    float* Ksum = (float*)(ws + 8519680);             // 2048
    float* fqb  = (float*)(ws + 8521728);             // 2048
    float* fkb  = (float*)(ws + 8523776);             // 2048
    bf16*  WqpT = (bf16*)(ws + 8525824);              // 262144
    bf16*  WkpT = (bf16*)(ws + 8787968);              // 262144
    bf16*  WvT  = (bf16*)(ws + 9050112);              // 262144
    bf16*  WoT  = (bf16*)(ws + 9312256);              // 65536
    bf16*  KVT  = (bf16*)(ws + 9377792);              // 65536  -> total ~9.44 MB

    prep_kernel<<<dim3(1156), 256, 0, stream>>>(Wq, bq, Wk, bk, Wv, Wo, proj,
                                                WqpT, WkpT, WvT, WoT, fqb, fkb);
    kv_kernel<<<dim3(NSLICE, 8), 256, 0, stream>>>(x, WkpT, fkb, WvT, bv, pKV, pSum);
    reduce_kernel<<<dim3(130), 256, 0, stream>>>(pKV, pSum, KVT, Ksum);
    out_kernel<<<dim3(NCH128), 256, 0, stream>>>(x, WqpT, fqb, KVT, Ksum, WoT, bo, out);
}

// Round 5
// 301.192 us; speedup vs baseline: 8.5580x; 1.0481x over previous
//
#include <hip/hip_runtime.h>

// Performer attention (HyperGTConv): N=50000, C=256, H=8, D=M=64.
// Round 5: kill the 8x redundant x fetch in kv_kernel.
//  - kv grid flattened to 512 blocks with XCD-aware swizzle: the 8 head-blocks
//    sharing an x slice are co-resident on ONE XCD -> L2 serves 7 of 8 reads.
//  - optional bf16 x copy (xb) when ws_size permits: halves x bytes and makes
//    A-frags single 16B loads. Host-side ws_size check; fp32 fallback.

#define NN      50000
#define HDIM    512
#define EPSF    1e-6f
#define SCALE   0.044194173824159224f   // (1/sqrt(64)) * 64^(-1/4)
#define NCH128  391                     // ceil(50000/128)
#define NSLICE  64                      // kv slices per head
#define LDPA    72                      // [32][72] bf16 row-major strip buf
#define LDPB    40                      // [64][40] bf16 transposed strip buf

typedef __bf16 bf16;
typedef __bf16 bf16x8 __attribute__((ext_vector_type(8)));
typedef float  f32x4  __attribute__((ext_vector_type(4)));

#define MFMA(a, b, c) __builtin_amdgcn_mfma_f32_16x16x32_bf16((a), (b), (c), 0, 0, 0)

__device__ __forceinline__ void lds_fence() {
    asm volatile("s_waitcnt lgkmcnt(0)" ::: "memory");
}

__device__ __forceinline__ bf16x8 load_x_frag_f32(const float* __restrict__ xrow, int col) {
    const float4 a = *reinterpret_cast<const float4*>(xrow + col);
    const float4 b = *reinterpret_cast<const float4*>(xrow + col + 4);
    bf16x8 r;
    r[0] = (bf16)a.x; r[1] = (bf16)a.y; r[2] = (bf16)a.z; r[3] = (bf16)a.w;
    r[4] = (bf16)b.x; r[5] = (bf16)b.y; r[6] = (bf16)b.z; r[7] = (bf16)b.w;
    return r;
}

// ---------- xconv: x fp32 -> bf16 ----------
__global__ void xconv_kernel(const float* __restrict__ x, bf16* __restrict__ xb)
{
    for (int i8 = blockIdx.x * 256 + threadIdx.x; i8 < NN * 256 / 8;
         i8 += gridDim.x * 256) {
        const float4 a = reinterpret_cast<const float4*>(x)[i8 * 2];
        const float4 b = reinterpret_cast<const float4*>(x)[i8 * 2 + 1];
        bf16x8 r;
        r[0] = (bf16)a.x; r[1] = (bf16)a.y; r[2] = (bf16)a.z; r[3] = (bf16)a.w;
        r[4] = (bf16)b.x; r[5] = (bf16)b.y; r[6] = (bf16)b.z; r[7] = (bf16)b.w;
        reinterpret_cast<bf16x8*>(xb)[i8] = r;
    }
}

// ---------- prep: folded + transposed bf16 weights ----------
__global__ void prep_kernel(const float* __restrict__ Wq, const float* __restrict__ bq,
                            const float* __restrict__ Wk, const float* __restrict__ bk,
                            const float* __restrict__ Wv, const float* __restrict__ Wo,
                            const float* __restrict__ proj,
                            bf16* __restrict__ WqpT, bf16* __restrict__ WkpT,
                            bf16* __restrict__ WvT, bf16* __restrict__ WoT,
                            float* __restrict__ fqb, float* __restrict__ fkb)
{
    const int t = blockIdx.x * 256 + threadIdx.x;
    if (t < 131072) {                       // WqpT/WkpT [h*64+m][c] = sum_d W[c][h,d] proj[m][d]
        const int row = t >> 8, c = t & 255;
        const int hh = row >> 6, m = row & 63;
        const float* pr = proj + m * 64;
        const float* wq = Wq + (size_t)c * HDIM + hh * 64;
        const float* wk = Wk + (size_t)c * HDIM + hh * 64;
        float sq = 0.f, sk = 0.f;
        for (int d = 0; d < 64; ++d) { const float p = pr[d]; sq += wq[d] * p; sk += wk[d] * p; }
        WqpT[(size_t)row * 256 + c] = (bf16)sq;
        WkpT[(size_t)row * 256 + c] = (bf16)sk;
    } else if (t < 262144) {                // WvT[col][c] = Wv[c][col]
        const int i = t - 131072;
        const int col = i >> 8, c = i & 255;
        WvT[i] = (bf16)Wv[(size_t)c * HDIM + col];
    } else if (t < 262144 + 32768) {        // WoT[j][dp] = Wo[dp][j]
        const int i = t - 262144;
        const int j = i >> 9, dp = i & 511;
        WoT[i] = (bf16)Wo[(size_t)dp * 64 + j];
    } else if (t < 262144 + 32768 + 1024) { // fqb/fkb[h*64+m] = sum_d b[h,d] proj[m][d]
        const int i = t - 262144 - 32768;
        const int which = i >> 9, row = i & 511;
        const int hh = row >> 6, m = row & 63;
        const float* pr = proj + m * 64;
        const float* b = (which ? bk : bq) + hh * 64;
        float s = 0.f;
        for (int d = 0; d < 64; ++d) s += b[d] * pr[d];
        (which ? fkb : fqb)[row] = s;
    }
}

// ---------- kernel 1: Kp, V, KV partials (XCD-swizzled, barrier-free loop) ----------
template <bool USE_XB>
__global__ __launch_bounds__(256, 2)
void kv_kernel(const float* __restrict__ x, const bf16* __restrict__ xb,
               const bf16* __restrict__ WkpT, const float* __restrict__ fkb,
               const bf16* __restrict__ WvT,  const float* __restrict__ bv,
               float* __restrict__ pKV, float* __restrict__ pSum)
{
    __shared__ __align__(16) char pool[4 * 2 * 64 * LDPB * 2];   // 40960 B
    const int t  = threadIdx.x;
    const int w  = t >> 6;
    const int l  = t & 63;
    const int lr = l & 15;
    const int lk = l >> 4;

    // XCD swizzle: same slice s, all 8 heads -> same XCD (id % 8 constant)
    const int id  = blockIdx.x;          // 0..511
    const int xcd = id & 7;
    const int pos = id >> 3;             // 0..63
    const int h   = pos >> 3;            // 0..7
    const int bx  = xcd * 8 + (pos & 7); // 0..63

    bf16* kptbuf = (bf16*)(pool + w * (2 * 64 * LDPB * 2));   // [64 m][40 n]
    bf16* vtbuf  = kptbuf + 64 * LDPB;                        // [64 d][40 n]

    f32x4 kvacc[16];
#pragma unroll
    for (int i = 0; i < 16; ++i) kvacc[i] = (f32x4){0.f, 0.f, 0.f, 0.f};
    float ksum_acc[4] = {0.f, 0.f, 0.f, 0.f};

    float fkbc[4], bvc[4];
#pragma unroll
    for (int q = 0; q < 4; ++q) {
        fkbc[q] = fkb[h * 64 + q * 16 + lr];
        bvc[q]  = bv [h * 64 + q * 16 + lr];
    }

    for (int chunk = bx; chunk < NCH128; chunk += NSLICE) {
        const int nbase = chunk * 128 + w * 32;
        const int r0 = min(nbase + lr,      NN - 1);
        const int r1 = min(nbase + 16 + lr, NN - 1);
        const float* xr0 = x + (size_t)r0 * 256;
        const float* xr1 = x + (size_t)r1 * 256;
        const bf16*  xb0 = xb + (size_t)r0 * 256;
        const bf16*  xb1 = xb + (size_t)r1 * 256;

        // ---- Kfeat = x@Wkp + fkb ; V = x@Wv + bv ----
        f32x4 fK[2][4], aV[2][4];
#pragma unroll
        for (int q = 0; q < 4; ++q) {
            fK[0][q] = (f32x4){fkbc[q], fkbc[q], fkbc[q], fkbc[q]};
            fK[1][q] = fK[0][q];
            aV[0][q] = (f32x4){bvc[q], bvc[q], bvc[q], bvc[q]};
            aV[1][q] = aV[0][q];
        }
#pragma unroll
        for (int kk = 0; kk < 8; ++kk) {
            const int off = kk * 32 + lk * 8;
            const bf16x8 xa0 = USE_XB ? *reinterpret_cast<const bf16x8*>(xb0 + off)
                                      : load_x_frag_f32(xr0, off);
            const bf16x8 xa1 = USE_XB ? *reinterpret_cast<const bf16x8*>(xb1 + off)
                                      : load_x_frag_f32(xr1, off);
#pragma unroll
            for (int mt = 0; mt < 4; ++mt) {
                const bf16x8 wb = *reinterpret_cast<const bf16x8*>(
                    &WkpT[(size_t)(h * 64 + mt * 16 + lr) * 256 + off]);
                fK[0][mt] = MFMA(xa0, wb, fK[0][mt]);
                fK[1][mt] = MFMA(xa1, wb, fK[1][mt]);
            }
#pragma unroll
            for (int ct = 0; ct < 4; ++ct) {
                const bf16x8 wb = *reinterpret_cast<const bf16x8*>(
                    &WvT[(size_t)(h * 64 + ct * 16 + lr) * 256 + off]);
                aV[0][ct] = MFMA(xa0, wb, aV[0][ct]);
                aV[1][ct] = MFMA(xa1, wb, aV[1][ct]);
            }
        }

        lds_fence();   // previous iteration's kpa/vb reads drained
        // ---- exp -> Kp^T [m][n]; V^T [d][n]; zero invalid rows ----
#pragma unroll
        for (int rt = 0; rt < 2; ++rt)
#pragma unroll
            for (int q = 0; q < 4; ++q)
#pragma unroll
                for (int r = 0; r < 4; ++r) {
                    const int nl = rt * 16 + lk * 4 + r;
                    const bool valid = (nbase + nl) < NN;
                    const float kpv = valid ? (__expf(SCALE * fK[rt][q][r]) + EPSF) : 0.f;
                    ksum_acc[q] += kpv;
                    kptbuf[(q * 16 + lr) * LDPB + nl] = (bf16)kpv;
                    vtbuf [(q * 16 + lr) * LDPB + nl] = valid ? (bf16)aV[rt][q][r] : (bf16)0.f;
                }
        lds_fence();   // writes visible to whole wave

        // ---- KV += Kp^T @ V ----
        bf16x8 kpa[4], vb[4];
#pragma unroll
        for (int mt = 0; mt < 4; ++mt)
            kpa[mt] = *reinterpret_cast<const bf16x8*>(&kptbuf[(mt * 16 + lr) * LDPB + lk * 8]);
#pragma unroll
        for (int dt = 0; dt < 4; ++dt)
            vb[dt] = *reinterpret_cast<const bf16x8*>(&vtbuf[(dt * 16 + lr) * LDPB + lk * 8]);
#pragma unroll
        for (int mt = 0; mt < 4; ++mt)
#pragma unroll
            for (int dt = 0; dt < 4; ++dt)
                kvacc[mt * 4 + dt] = MFMA(kpa[mt], vb[dt], kvacc[mt * 4 + dt]);
    }

    // ---- epilogue: ksum shfl reduce; block-level KV reduce ----
#pragma unroll
    for (int q = 0; q < 4; ++q) {
        float s = ksum_acc[q];
        s += __shfl_xor(s, 16, 64);
        s += __shfl_xor(s, 32, 64);
        ksum_acc[q] = s;
    }

    float* red   = (float*)pool;            // 32768 B
    float* sredp = (float*)(pool + 33024);  // 1024 B

    __syncthreads();   // S1
    if (lk == 0) {
#pragma unroll
        for (int q = 0; q < 4; ++q) sredp[w * 64 + q * 16 + lr] = ksum_acc[q];
    }
    if (w >= 2) {
#pragma unroll
        for (int mt = 0; mt < 4; ++mt)
#pragma unroll
            for (int dt = 0; dt < 4; ++dt)
#pragma unroll
                for (int r = 0; r < 4; ++r)
                    red[(w - 2) * 4096 + (mt * 16 + lk * 4 + r) * 64 + dt * 16 + lr] =
                        kvacc[mt * 4 + dt][r];
    }
    __syncthreads();   // S2
    if (w < 2) {
#pragma unroll
        for (int mt = 0; mt < 4; ++mt)
#pragma unroll
            for (int dt = 0; dt < 4; ++dt)
#pragma unroll
                for (int r = 0; r < 4; ++r)
                    kvacc[mt * 4 + dt][r] +=
                        red[w * 4096 + (mt * 16 + lk * 4 + r) * 64 + dt * 16 + lr];
    }
    __syncthreads();   // S3
    if (w == 1) {
#pragma unroll
        for (int mt = 0; mt < 4; ++mt)
#pragma unroll
            for (int dt = 0; dt < 4; ++dt)
#pragma unroll
                for (int r = 0; r < 4; ++r)
                    red[(mt * 16 + lk * 4 + r) * 64 + dt * 16 + lr] = kvacc[mt * 4 + dt][r];
    }
    __syncthreads();   // S4
    if (w == 0) {
        float* dst = pKV + ((size_t)h * NSLICE + bx) * 4096;
#pragma unroll
        for (int mt = 0; mt < 4; ++mt)
#pragma unroll
            for (int dt = 0; dt < 4; ++dt)
#pragma unroll
                for (int r = 0; r < 4; ++r) {
                    const int md = (mt * 16 + lk * 4 + r) * 64 + dt * 16 + lr;
                    dst[md] = kvacc[mt * 4 + dt][r] + red[md];
                }
    }
    if (t < 64)
        pSum[((size_t)h * NSLICE + bx) * 64 + t] =
            sredp[t] + sredp[64 + t] + sredp[128 + t] + sredp[192 + t];
}

// ---------- reduce: partials -> KVT bf16 [h][d][m] + Ksum fp32 ----------
__global__ void reduce_kernel(const float* __restrict__ pKV, const float* __restrict__ pSum,
                              bf16* __restrict__ KVT, float* __restrict__ Ksum)
{
    const int idx = blockIdx.x * 256 + threadIdx.x;
    if (idx < 8 * 4096) {
        const int h = idx >> 12, md = idx & 4095;
        const int m = md >> 6, d = md & 63;
        float s = 0.f;
        for (int b = 0; b < NSLICE; ++b) s += pKV[((size_t)h * NSLICE + b) * 4096 + md];
        KVT[h * 4096 + d * 64 + m] = (bf16)s;
    } else if (idx < 8 * 4096 + 512) {
        const int j = idx - 8 * 4096;
        const int h = j >> 6, m = j & 63;
        float s = 0.f;
        for (int b = 0; b < NSLICE; ++b) s += pSum[((size_t)h * NSLICE + b) * 64 + m];
        Ksum[j] = s;
    }
}

// ---------- kernel 3: Qp -> Z -> out (zero barriers) ----------
template <bool USE_XB>
__global__ __launch_bounds__(256, 2)
void out_kernel(const float* __restrict__ x, const bf16* __restrict__ xb,
                const bf16* __restrict__ WqpT, const float* __restrict__ fqb,
                const bf16* __restrict__ KVT, const float* __restrict__ Ksum,
                const bf16* __restrict__ WoT, const float* __restrict__ bo,
                float* __restrict__ out)
{
    __shared__ __align__(16) bf16 tbufs[4][32 * LDPA];   // 4 x 4608 B
    const int t  = threadIdx.x;
    const int w  = t >> 6;
    const int l  = t & 63;
    const int lr = l & 15;
    const int lk = l >> 4;
    bf16* tbuf = tbufs[w];
    const int nbase = blockIdx.x * 128 + w * 32;

    const int r0 = min(nbase + lr,      NN - 1);
    const int r1 = min(nbase + 16 + lr, NN - 1);
    const float* xr0 = x + (size_t)r0 * 256;
    const float* xr1 = x + (size_t)r1 * 256;
    const bf16*  xb0 = xb + (size_t)r0 * 256;
    const bf16*  xb1 = xb + (size_t)r1 * 256;
    bf16x8 xa[2][8];
#pragma unroll
    for (int kk = 0; kk < 8; ++kk) {
        const int off = kk * 32 + lk * 8;
        xa[0][kk] = USE_XB ? *reinterpret_cast<const bf16x8*>(xb0 + off)
                           : load_x_frag_f32(xr0, off);
        xa[1][kk] = USE_XB ? *reinterpret_cast<const bf16x8*>(xb1 + off)
                           : load_x_frag_f32(xr1, off);
    }

    f32x4 oacc[2][4];
#pragma unroll
    for (int jt = 0; jt < 4; ++jt) {
        const float b = bo[jt * 16 + lr];
        oacc[0][jt] = (f32x4){b, b, b, b};
        oacc[1][jt] = oacc[0][jt];
    }

    for (int h = 0; h < 8; ++h) {
        // ---- Qfeat = x@Wqp + fqb ----
        f32x4 fQ[2][4];
#pragma unroll
        for (int mt = 0; mt < 4; ++mt) {
            const float b = fqb[h * 64 + mt * 16 + lr];
            fQ[0][mt] = (f32x4){b, b, b, b};
            fQ[1][mt] = fQ[0][mt];
        }
#pragma unroll
        for (int kk = 0; kk < 8; ++kk) {
#pragma unroll
            for (int mt = 0; mt < 4; ++mt) {
                const bf16x8 wb = *reinterpret_cast<const bf16x8*>(
                    &WqpT[(size_t)(h * 64 + mt * 16 + lr) * 256 + kk * 32 + lk * 8]);
                fQ[0][mt] = MFMA(xa[0][kk], wb, fQ[0][mt]);
                fQ[1][mt] = MFMA(xa[1][kk], wb, fQ[1][mt]);
            }
        }

        // ---- qp = exp(SCALE*feat)+eps; den partials; write qp -> tbuf ----
        lds_fence();   // drain previous head's za reads
        float denp[2][4] = {{0.f,0.f,0.f,0.f},{0.f,0.f,0.f,0.f}};
#pragma unroll
        for (int rt = 0; rt < 2; ++rt)
#pragma unroll
            for (int mt = 0; mt < 4; ++mt) {
                const float ks = Ksum[h * 64 + mt * 16 + lr];
#pragma unroll
                for (int r = 0; r < 4; ++r) {
                    const float qp = __expf(SCALE * fQ[rt][mt][r]) + EPSF;
                    denp[rt][r] += qp * ks;
                    tbuf[(rt * 16 + lk * 4 + r) * LDPA + mt * 16 + lr] = (bf16)qp;
                }
            }
#pragma unroll
        for (int rt = 0; rt < 2; ++rt)
#pragma unroll
            for (int r = 0; r < 4; ++r) {
                float s = denp[rt][r];
                s += __shfl_xor(s, 1, 64);
                s += __shfl_xor(s, 2, 64);
                s += __shfl_xor(s, 4, 64);
                s += __shfl_xor(s, 8, 64);
                denp[rt][r] = s;
            }
        lds_fence();

        // ---- num = Qp @ KV ----
        bf16x8 qpa[2][2];
#pragma unroll
        for (int rt = 0; rt < 2; ++rt)
#pragma unroll
            for (int kk = 0; kk < 2; ++kk)
                qpa[rt][kk] = *reinterpret_cast<const bf16x8*>(
                    &tbuf[(rt * 16 + lr) * LDPA + kk * 32 + lk * 8]);
        f32x4 num[2][4];
#pragma unroll
        for (int dt = 0; dt < 4; ++dt) { num[0][dt] = (f32x4){0.f,0.f,0.f,0.f}; num[1][dt] = num[0][dt]; }
#pragma unroll
        for (int dt = 0; dt < 4; ++dt)
#pragma unroll
            for (int kk = 0; kk < 2; ++kk) {
                const bf16x8 kvb = *reinterpret_cast<const bf16x8*>(
                    &KVT[h * 4096 + (dt * 16 + lr) * 64 + kk * 32 + lk * 8]);
                num[0][dt] = MFMA(qpa[0][kk], kvb, num[0][dt]);
                num[1][dt] = MFMA(qpa[1][kk], kvb, num[1][dt]);
            }

        // ---- z = num/den -> tbuf ----
        lds_fence();   // drain qpa reads
#pragma unroll
        for (int rt = 0; rt < 2; ++rt)
#pragma unroll
            for (int dt = 0; dt < 4; ++dt)
#pragma unroll
                for (int r = 0; r < 4; ++r)
                    tbuf[(rt * 16 + lk * 4 + r) * LDPA + dt * 16 + lr] =
                        (bf16)(num[rt][dt][r] / (denp[rt][r] + EPSF));
        lds_fence();

        // ---- out += Z @ Wo_h ----
        bf16x8 za[2][2];
#pragma unroll
        for (int rt = 0; rt < 2; ++rt)
#pragma unroll
            for (int kk = 0; kk < 2; ++kk)
                za[rt][kk] = *reinterpret_cast<const bf16x8*>(
                    &tbuf[(rt * 16 + lr) * LDPA + kk * 32 + lk * 8]);
#pragma unroll
        for (int jt = 0; jt < 4; ++jt)
#pragma unroll
            for (int kk = 0; kk < 2; ++kk) {
                const bf16x8 wo = *reinterpret_cast<const bf16x8*>(
                    &WoT[(size_t)(jt * 16 + lr) * HDIM + h * 64 + kk * 32 + lk * 8]);
                oacc[0][jt] = MFMA(za[0][kk], wo, oacc[0][jt]);
                oacc[1][jt] = MFMA(za[1][kk], wo, oacc[1][jt]);
            }
    }

#pragma unroll
    for (int rt = 0; rt < 2; ++rt)
#pragma unroll
        for (int jt = 0; jt < 4; ++jt)
#pragma unroll
            for (int r = 0; r < 4; ++r) {
                const int n = nbase + rt * 16 + lk * 4 + r;
                if (n < NN) out[(size_t)n * 64 + jt * 16 + lr] = oacc[rt][jt][r];
            }
}

extern "C" void kernel_launch(void* const* d_in, const int* in_sizes, int n_in,
                              void* d_out, int out_size, void* d_ws, size_t ws_size,
                              hipStream_t stream) {
    const float* x    = (const float*)d_in[0];
    const float* Wq   = (const float*)d_in[1];
    const float* bq   = (const float*)d_in[2];
    const float* Wk   = (const float*)d_in[3];
    const float* bk   = (const float*)d_in[4];
    const float* Wv   = (const float*)d_in[5];
    const float* bv   = (const float*)d_in[6];
    const float* Wo   = (const float*)d_in[7];
    const float* bo   = (const float*)d_in[8];
    const float* proj = (const float*)d_in[9];
    float* out = (float*)d_out;

    // workspace layout (bytes)
    char* ws = (char*)d_ws;
    float* pKV  = (float*)ws;                         // 8*64*4096*4 = 8388608
    float* pSum = (float*)(ws + 8388608);             // 131072
    float* Ksum = (float*)(ws + 8519680);             // 2048
    float* fqb  = (float*)(ws + 8521728);             // 2048
    float* fkb  = (float*)(ws + 8523776);             // 2048
    bf16*  WqpT = (bf16*)(ws + 8525824);              // 262144
    bf16*  WkpT = (bf16*)(ws + 8787968);              // 262144
    bf16*  WvT  = (bf16*)(ws + 9050112);              // 262144
    bf16*  WoT  = (bf16*)(ws + 9312256);              // 65536
    bf16*  KVT  = (bf16*)(ws + 9377792);              // 65536
    bf16*  xb   = (bf16*)(ws + 9443328);              // 50000*256*2 = 25600000
    const bool use_xb = ws_size >= (size_t)(9443328 + 25600000);

    prep_kernel<<<dim3(1156), 256, 0, stream>>>(Wq, bq, Wk, bk, Wv, Wo, proj,
                                                WqpT, WkpT, WvT, WoT, fqb, fkb);
    if (use_xb) {
        xconv_kernel<<<dim3(2048), 256, 0, stream>>>(x, xb);
        kv_kernel<true><<<dim3(512), 256, 0, stream>>>(x, xb, WkpT, fkb, WvT, bv,
                                                       pKV, pSum);
        reduce_kernel<<<dim3(130), 256, 0, stream>>>(pKV, pSum, KVT, Ksum);
        out_kernel<true><<<dim3(NCH128), 256, 0, stream>>>(x, xb, WqpT, fqb, KVT, Ksum,
                                                           WoT, bo, out);
    } else {
        kv_kernel<false><<<dim3(512), 256, 0, stream>>>(x, xb, WkpT, fkb, WvT, bv,
                                                        pKV, pSum);
        reduce_kernel<<<dim3(130), 256, 0, stream>>>(pKV, pSum, KVT, Ksum);
        out_kernel<false><<<dim3(NCH128), 256, 0, stream>>>(x, xb, WqpT, fqb, KVT, Ksum,
                                                            WoT, bo, out);
    }
}